// Round 1
// baseline (303.641 us; speedup 1.0000x reference)
//
#include <hip/hip_runtime.h>

#define BDIM 256

constexpr int K      = 32;
constexpr int L1     = 1024;
constexpr int L2C    = 15;
constexpr int L3C    = 32;
constexpr int COUNT  = 9;
constexpr int W1COLS = COUNT * (L2C + 1); // 144
constexpr int W2COLS = COUNT * L3C;       // 288

__device__ __forceinline__ float clip01(float x) {
    return fminf(fmaxf(x, 0.0f), 1.0f);
}

__global__ __launch_bounds__(BDIM) void nnue_fused(
    const float* __restrict__ us,
    const float* __restrict__ them,
    const int*   __restrict__ wi,
    const float* __restrict__ wv,
    const int*   __restrict__ bi,
    const float* __restrict__ bvv,
    const int*   __restrict__ lsi,
    const float* __restrict__ W_ft,
    const float* __restrict__ b_ft,
    const float* __restrict__ W1,
    const float* __restrict__ b1,
    const float* __restrict__ W2,
    const float* __restrict__ b2,
    const float* __restrict__ W3,
    const float* __restrict__ b3,
    float* __restrict__ out)
{
    const int b = blockIdx.x;
    const int t = threadIdx.x;

    __shared__ int   s_idx[2 * K];
    __shared__ float s_val[2 * K];
    __shared__ float s_l0[2 * L1];   // clipped [A | Bv]
    __shared__ float s_red[4 * 16];
    __shared__ float s_v[2 * L2C];   // 30: [l1x^2 * c | l1x * c]
    __shared__ float s_p2[L3C];
    __shared__ float s_l1f;

    // ---- stage sparse indices/values (wave-uniform broadcast later) ----
    if (t < K)          { s_idx[t] = wi[b * K + t];        s_val[t] = wv[b * K + t]; }
    else if (t < 2 * K) { s_idx[t] = bi[b * K + (t - K)];  s_val[t] = bvv[b * K + (t - K)]; }
    __syncthreads();

    // ---- feature transform: each thread owns float4 slice of wp and bp ----
    const int c4 = t * 4;
    float4 accW = *(const float4*)(b_ft + c4);
    float4 accB = accW;

    #pragma unroll 4
    for (int k = 0; k < K; ++k) {
        const float  vwk = s_val[k];
        const float  vbk = s_val[K + k];
        const float4 rw  = *(const float4*)(W_ft + ((long)s_idx[k]     << 10) + c4);
        const float4 rb  = *(const float4*)(W_ft + ((long)s_idx[K + k] << 10) + c4);
        accW.x = fmaf(vwk, rw.x, accW.x);
        accW.y = fmaf(vwk, rw.y, accW.y);
        accW.z = fmaf(vwk, rw.z, accW.z);
        accW.w = fmaf(vwk, rw.w, accW.w);
        accB.x = fmaf(vbk, rb.x, accB.x);
        accB.y = fmaf(vbk, rb.y, accB.y);
        accB.z = fmaf(vbk, rb.z, accB.z);
        accB.w = fmaf(vbk, rb.w, accB.w);
    }

    // ---- perspective select + clip, stage to LDS ----
    const float u  = us[b];
    const float th = them[b];
    float4 A, Bv;
    A.x  = clip01(u * accW.x + th * accB.x);
    A.y  = clip01(u * accW.y + th * accB.y);
    A.z  = clip01(u * accW.z + th * accB.z);
    A.w  = clip01(u * accW.w + th * accB.w);
    Bv.x = clip01(u * accB.x + th * accW.x);
    Bv.y = clip01(u * accB.y + th * accW.y);
    Bv.z = clip01(u * accB.z + th * accW.z);
    Bv.w = clip01(u * accB.w + th * accW.w);
    *(float4*)(s_l0 + c4)      = A;
    *(float4*)(s_l0 + L1 + c4) = Bv;
    __syncthreads();

    const int   idx = lsi[b];
    const float cc  = 127.0f / 128.0f;

    // ---- layer 1: x1[j] = l0p . W1[:, idx*16 + j], j = 0..15 ----
    float p[16];
    #pragma unroll
    for (int j = 0; j < 16; ++j) p[j] = 0.0f;

    const float* W1sel = W1 + idx * (L2C + 1);
    #pragma unroll
    for (int q = 0; q < 4; ++q) {
        const int e = c4 + q;
        float l0p;
        if (e < 512) l0p = s_l0[e] * s_l0[e + 512];          // s0*s1 from A
        else         l0p = s_l0[e + 512] * s_l0[e + 1024];   // s2*s3 from Bv
        l0p *= cc;
        const float* wrow = W1sel + e * W1COLS;
        #pragma unroll
        for (int j = 0; j < 16; ++j) p[j] = fmaf(l0p, wrow[j], p[j]);
    }

    // wave shuffle-reduce 16 partials, then combine 4 waves via LDS
    const int lane = t & 63;
    const int wid  = t >> 6;
    #pragma unroll
    for (int j = 0; j < 16; ++j) {
        float v = p[j];
        v += __shfl_down(v, 32);
        v += __shfl_down(v, 16);
        v += __shfl_down(v, 8);
        v += __shfl_down(v, 4);
        v += __shfl_down(v, 2);
        v += __shfl_down(v, 1);
        if (lane == 0) s_red[wid * 16 + j] = v;
    }
    __syncthreads();

    if (t < 16) {
        float x1 = s_red[t] + s_red[16 + t] + s_red[32 + t] + s_red[48 + t]
                 + b1[idx * (L2C + 1) + t];
        if (t == 15) {
            s_l1f = x1;                    // pass-through term
        } else {
            float cx = clip01(x1);
            s_v[t]       = cx * cx * cc;   // squared half
            s_v[L2C + t] = cx * cc;        // linear half
        }
    }
    __syncthreads();

    // ---- layer 2 (30 -> 32) + layer 3 (32 -> 1), on first 32 threads ----
    if (t < L3C) {
        float acc = b2[idx * L3C + t];
        #pragma unroll
        for (int r = 0; r < 2 * L2C; ++r)
            acc = fmaf(s_v[r], W2[r * W2COLS + idx * L3C + t], acc);
        s_p2[t] = clip01(acc) * W3[t * COUNT + idx];
    }
    __syncthreads();

    if (t == 0) {
        float s = 0.0f;
        #pragma unroll
        for (int m = 0; m < L3C; ++m) s += s_p2[m];
        out[b] = s + b3[idx] + s_l1f;
    }
}

extern "C" void kernel_launch(void* const* d_in, const int* in_sizes, int n_in,
                              void* d_out, int out_size, void* d_ws, size_t ws_size,
                              hipStream_t stream) {
    const float* us   = (const float*)d_in[0];
    const float* them = (const float*)d_in[1];
    const int*   wi   = (const int*)  d_in[2];
    const float* wv   = (const float*)d_in[3];
    const int*   bi   = (const int*)  d_in[4];
    const float* bv   = (const float*)d_in[5];
    const int*   lsi  = (const int*)  d_in[6];
    const float* W_ft = (const float*)d_in[7];
    const float* b_ft = (const float*)d_in[8];
    const float* W1   = (const float*)d_in[9];
    const float* b1   = (const float*)d_in[10];
    const float* W2   = (const float*)d_in[11];
    const float* b2   = (const float*)d_in[12];
    const float* W3   = (const float*)d_in[13];
    const float* b3   = (const float*)d_in[14];
    float*       out  = (float*)d_out;

    const int Bn = in_sizes[0]; // 4096 batch rows
    nnue_fused<<<Bn, BDIM, 0, stream>>>(us, them, wi, wv, bi, bv, lsi,
                                        W_ft, b_ft, W1, b1, W2, b2, W3, b3, out);
}

// Round 2
// 268.997 us; speedup vs baseline: 1.1288x; 1.1288x over previous
//
#include <hip/hip_runtime.h>

#define BDIM 256

constexpr int K      = 32;
constexpr int L1     = 1024;
constexpr int L2C    = 15;
constexpr int L3C    = 32;
constexpr int COUNT  = 9;
constexpr int NF     = 22528;
constexpr int W1COLS = COUNT * (L2C + 1); // 144
constexpr int W2COLS = COUNT * L3C;       // 288

typedef __attribute__((ext_vector_type(4))) _Float16 half4;

__device__ __forceinline__ float clip01(float x) {
    return fminf(fmaxf(x, 0.0f), 1.0f);
}

// ---- fp32 -> fp16 conversion of W_ft into workspace ----
__global__ __launch_bounds__(256) void cvt_w_ft(const float* __restrict__ src,
                                                _Float16* __restrict__ dst, int n4) {
    const float4* s4 = (const float4*)src;
    half4*        d4 = (half4*)dst;
    for (int j = blockIdx.x * blockDim.x + threadIdx.x; j < n4;
         j += gridDim.x * blockDim.x) {
        float4 v = s4[j];
        half4 h;
        h.x = (_Float16)v.x; h.y = (_Float16)v.y;
        h.z = (_Float16)v.z; h.w = (_Float16)v.w;
        d4[j] = h;
    }
}

template <bool HALFW>
__global__ __launch_bounds__(BDIM) void nnue_fused(
    const float* __restrict__ us,
    const float* __restrict__ them,
    const int*   __restrict__ wi,
    const float* __restrict__ wv,
    const int*   __restrict__ bi,
    const float* __restrict__ bvv,
    const int*   __restrict__ lsi,
    const void*  __restrict__ W_ft,   // fp32 or fp16 table
    const float* __restrict__ b_ft,
    const float* __restrict__ W1,
    const float* __restrict__ b1,
    const float* __restrict__ W2,
    const float* __restrict__ b2,
    const float* __restrict__ W3,
    const float* __restrict__ b3,
    float* __restrict__ out)
{
    const int b = blockIdx.x;
    const int t = threadIdx.x;

    __shared__ int   s_idx[2 * K];
    __shared__ float s_val[2 * K];
    __shared__ float s_l0[2 * L1];   // clipped [A | Bv]
    __shared__ float s_red[4 * 16];
    __shared__ float s_v[2 * L2C];   // 30: [l1x^2 * c | l1x * c]
    __shared__ float s_p2[L3C];
    __shared__ float s_l1f;

    // ---- stage sparse indices/values ----
    if (t < K)          { s_idx[t] = wi[b * K + t];        s_val[t] = wv[b * K + t]; }
    else if (t < 2 * K) { s_idx[t] = bi[b * K + (t - K)];  s_val[t] = bvv[b * K + (t - K)]; }
    __syncthreads();

    // ---- feature transform: each thread owns cols [4t..4t+4) of wp and bp ----
    const int c4 = t * 4;
    float4 accW = *(const float4*)(b_ft + c4);
    float4 accB = accW;

    #pragma unroll 4
    for (int k = 0; k < K; ++k) {
        const float vwk = s_val[k];
        const float vbk = s_val[K + k];
        float4 rw, rb;
        if constexpr (HALFW) {
            const _Float16* Wh = (const _Float16*)W_ft;
            const half4 hw = *(const half4*)(Wh + ((long)s_idx[k]     << 10) + c4);
            const half4 hb = *(const half4*)(Wh + ((long)s_idx[K + k] << 10) + c4);
            rw.x = (float)hw.x; rw.y = (float)hw.y; rw.z = (float)hw.z; rw.w = (float)hw.w;
            rb.x = (float)hb.x; rb.y = (float)hb.y; rb.z = (float)hb.z; rb.w = (float)hb.w;
        } else {
            const float* Wf = (const float*)W_ft;
            rw = *(const float4*)(Wf + ((long)s_idx[k]     << 10) + c4);
            rb = *(const float4*)(Wf + ((long)s_idx[K + k] << 10) + c4);
        }
        accW.x = fmaf(vwk, rw.x, accW.x);
        accW.y = fmaf(vwk, rw.y, accW.y);
        accW.z = fmaf(vwk, rw.z, accW.z);
        accW.w = fmaf(vwk, rw.w, accW.w);
        accB.x = fmaf(vbk, rb.x, accB.x);
        accB.y = fmaf(vbk, rb.y, accB.y);
        accB.z = fmaf(vbk, rb.z, accB.z);
        accB.w = fmaf(vbk, rb.w, accB.w);
    }

    // ---- perspective select + clip, stage to LDS ----
    const float u  = us[b];
    const float th = them[b];
    float4 A, Bv;
    A.x  = clip01(u * accW.x + th * accB.x);
    A.y  = clip01(u * accW.y + th * accB.y);
    A.z  = clip01(u * accW.z + th * accB.z);
    A.w  = clip01(u * accW.w + th * accB.w);
    Bv.x = clip01(u * accB.x + th * accW.x);
    Bv.y = clip01(u * accB.y + th * accW.y);
    Bv.z = clip01(u * accB.z + th * accW.z);
    Bv.w = clip01(u * accB.w + th * accW.w);
    *(float4*)(s_l0 + c4)      = A;
    *(float4*)(s_l0 + L1 + c4) = Bv;
    __syncthreads();

    const int   idx = lsi[b];
    const float cc  = 127.0f / 128.0f;

    // ---- layer 1: x1[j] = l0p . W1[:, idx*16 + j], j = 0..15 ----
    float p[16];
    #pragma unroll
    for (int j = 0; j < 16; ++j) p[j] = 0.0f;

    const float* W1sel = W1 + idx * (L2C + 1);
    #pragma unroll
    for (int q = 0; q < 4; ++q) {
        const int e = c4 + q;
        float l0p;
        if (e < 512) l0p = s_l0[e] * s_l0[e + 512];          // s0*s1
        else         l0p = s_l0[e + 512] * s_l0[e + 1024];   // s2*s3
        l0p *= cc;
        const float* wrow = W1sel + e * W1COLS;
        #pragma unroll
        for (int j = 0; j < 16; ++j) p[j] = fmaf(l0p, wrow[j], p[j]);
    }

    // wave shuffle-reduce, then combine 4 waves via LDS
    const int lane = t & 63;
    const int wid  = t >> 6;
    #pragma unroll
    for (int j = 0; j < 16; ++j) {
        float v = p[j];
        v += __shfl_down(v, 32);
        v += __shfl_down(v, 16);
        v += __shfl_down(v, 8);
        v += __shfl_down(v, 4);
        v += __shfl_down(v, 2);
        v += __shfl_down(v, 1);
        if (lane == 0) s_red[wid * 16 + j] = v;
    }
    __syncthreads();

    if (t < 16) {
        float x1 = s_red[t] + s_red[16 + t] + s_red[32 + t] + s_red[48 + t]
                 + b1[idx * (L2C + 1) + t];
        if (t == 15) {
            s_l1f = x1;                    // pass-through term
        } else {
            float cx = clip01(x1);
            s_v[t]       = cx * cx * cc;   // squared half
            s_v[L2C + t] = cx * cc;        // linear half
        }
    }
    __syncthreads();

    // ---- layer 2 (30 -> 32) + layer 3 (32 -> 1) ----
    if (t < L3C) {
        float acc = b2[idx * L3C + t];
        #pragma unroll
        for (int r = 0; r < 2 * L2C; ++r)
            acc = fmaf(s_v[r], W2[r * W2COLS + idx * L3C + t], acc);
        s_p2[t] = clip01(acc) * W3[t * COUNT + idx];
    }
    __syncthreads();

    if (t == 0) {
        float s = 0.0f;
        #pragma unroll
        for (int m = 0; m < L3C; ++m) s += s_p2[m];
        out[b] = s + b3[idx] + s_l1f;
    }
}

extern "C" void kernel_launch(void* const* d_in, const int* in_sizes, int n_in,
                              void* d_out, int out_size, void* d_ws, size_t ws_size,
                              hipStream_t stream) {
    const float* us   = (const float*)d_in[0];
    const float* them = (const float*)d_in[1];
    const int*   wi   = (const int*)  d_in[2];
    const float* wv   = (const float*)d_in[3];
    const int*   bi   = (const int*)  d_in[4];
    const float* bv   = (const float*)d_in[5];
    const int*   lsi  = (const int*)  d_in[6];
    const float* W_ft = (const float*)d_in[7];
    const float* b_ft = (const float*)d_in[8];
    const float* W1   = (const float*)d_in[9];
    const float* b1   = (const float*)d_in[10];
    const float* W2   = (const float*)d_in[11];
    const float* b2   = (const float*)d_in[12];
    const float* W3   = (const float*)d_in[13];
    const float* b3   = (const float*)d_in[14];
    float*       out  = (float*)d_out;

    const int Bn = in_sizes[0]; // 4096 batch rows
    const size_t needed = (size_t)NF * L1 * sizeof(_Float16); // 46.1 MB

    if (ws_size >= needed) {
        _Float16* Wh = (_Float16*)d_ws;
        const int n4 = (NF * L1) / 4;
        cvt_w_ft<<<2048, 256, 0, stream>>>(W_ft, Wh, n4);
        nnue_fused<true><<<Bn, BDIM, 0, stream>>>(us, them, wi, wv, bi, bv, lsi,
                                                  (const void*)Wh, b_ft, W1, b1,
                                                  W2, b2, W3, b3, out);
    } else {
        nnue_fused<false><<<Bn, BDIM, 0, stream>>>(us, them, wi, wv, bi, bv, lsi,
                                                   (const void*)W_ft, b_ft, W1, b1,
                                                   W2, b2, W3, b3, out);
    }
}

// Round 4
// 249.853 us; speedup vs baseline: 1.2153x; 1.0766x over previous
//
#include <hip/hip_runtime.h>

#define BDIM 256

constexpr int K      = 32;
constexpr int L1     = 1024;
constexpr int L2C    = 15;
constexpr int L3C    = 32;
constexpr int COUNT  = 9;
constexpr int NF     = 22528;
constexpr int W1COLS = COUNT * (L2C + 1); // 144
constexpr int W2COLS = COUNT * L3C;       // 288

typedef __attribute__((ext_vector_type(4))) _Float16 half4;
typedef __attribute__((ext_vector_type(8))) _Float16 half8;
typedef __attribute__((ext_vector_type(4))) float    f32x4;

__device__ __forceinline__ float clip01(float x) {
    return fminf(fmaxf(x, 0.0f), 1.0f);
}

// ---- fp32 -> fp16 conversion of W_ft into workspace ----
// Nontemporal load of the dead fp32 stream so it doesn't churn L2/L3,
// keeping the fp16 table warm for the gather kernel.
__global__ __launch_bounds__(256) void cvt_w_ft(const float* __restrict__ src,
                                                _Float16* __restrict__ dst, int n4) {
    const f32x4* s4 = (const f32x4*)src;
    half4*       d4 = (half4*)dst;
    for (int j = blockIdx.x * blockDim.x + threadIdx.x; j < n4;
         j += gridDim.x * blockDim.x) {
        f32x4 v = __builtin_nontemporal_load(s4 + j);
        half4 h;
        h.x = (_Float16)v.x; h.y = (_Float16)v.y;
        h.z = (_Float16)v.z; h.w = (_Float16)v.w;
        d4[j] = h;
    }
}

// ---- fused NNUE forward, fp16 feature table ----
// Threads 0..127: white perspective, cols [8tc, 8tc+8); threads 128..255: black.
__global__ __launch_bounds__(BDIM) void nnue_fused_h(
    const float* __restrict__ us,
    const float* __restrict__ them,
    const int*   __restrict__ wi,
    const float* __restrict__ wv,
    const int*   __restrict__ bi,
    const float* __restrict__ bvv,
    const int*   __restrict__ lsi,
    const _Float16* __restrict__ Wh,
    const float* __restrict__ b_ft,
    const float* __restrict__ W1,
    const float* __restrict__ b1,
    const float* __restrict__ W2,
    const float* __restrict__ b2,
    const float* __restrict__ W3,
    const float* __restrict__ b3,
    float* __restrict__ out)
{
    const int b = blockIdx.x;
    const int t = threadIdx.x;

    __shared__ int   s_idx[2 * K];
    __shared__ float s_val[2 * K];
    __shared__ float s_wp[L1];       // white accumulator
    __shared__ float s_bp[L1];       // black accumulator
    __shared__ float s_red[4 * 16];
    __shared__ float s_v[2 * L2C];
    __shared__ float s_p2[L3C];
    __shared__ float s_l1f;

    // ---- stage sparse indices/values ----
    if (t < K)          { s_idx[t] = wi[b * K + t];        s_val[t] = wv[b * K + t]; }
    else if (t < 2 * K) { s_idx[t] = bi[b * K + (t - K)];  s_val[t] = bvv[b * K + (t - K)]; }
    __syncthreads();

    // ---- feature transform: 16 B per row access per lane ----
    const int   half = t >> 7;        // 0 = white, 1 = black
    const int   tc   = t & 127;
    const int   c8   = tc * 8;
    const int*   idxs = s_idx + half * K;
    const float* vals = s_val + half * K;

    float acc[8];
    {
        const float4 bf0 = *(const float4*)(b_ft + c8);
        const float4 bf1 = *(const float4*)(b_ft + c8 + 4);
        acc[0] = bf0.x; acc[1] = bf0.y; acc[2] = bf0.z; acc[3] = bf0.w;
        acc[4] = bf1.x; acc[5] = bf1.y; acc[6] = bf1.z; acc[7] = bf1.w;
    }

    #pragma unroll 8
    for (int k = 0; k < K; ++k) {
        const float v   = vals[k];
        const half8 h   = *(const half8*)(Wh + ((long)idxs[k] << 10) + c8);
        #pragma unroll
        for (int j = 0; j < 8; ++j)
            acc[j] = fmaf(v, (float)h[j], acc[j]);
    }

    {
        float* dst = (half == 0 ? s_wp : s_bp) + c8;
        #pragma unroll
        for (int j = 0; j < 8; ++j) dst[j] = acc[j];
    }
    __syncthreads();

    const float u   = us[b];
    const float th  = them[b];
    const int   idx = lsi[b];
    const float cc  = 127.0f / 128.0f;

    // ---- layer 1: x1[j] = l0p . W1[:, idx*16 + j] ----
    float p[16];
    #pragma unroll
    for (int j = 0; j < 16; ++j) p[j] = 0.0f;

    const float* W1sel = W1 + idx * (L2C + 1);
    const int e0 = t * 4;
    #pragma unroll
    for (int q = 0; q < 4; ++q) {
        const int e = e0 + q;
        float l0p;
        if (e < 512) {
            // A[e] * A[e+512], A[i] = clip(u*wp[i] + th*bp[i])
            const float a0 = clip01(u * s_wp[e]       + th * s_bp[e]);
            const float a1 = clip01(u * s_wp[e + 512] + th * s_bp[e + 512]);
            l0p = a0 * a1;
        } else {
            // Bv[c] * Bv[c+512], c = e-512, Bv[i] = clip(u*bp[i] + th*wp[i])
            const int   c  = e - 512;
            const float b0 = clip01(u * s_bp[c] + th * s_wp[c]);
            const float b1v = clip01(u * s_bp[e] + th * s_wp[e]);
            l0p = b0 * b1v;
        }
        l0p *= cc;
        const float* wrow = W1sel + e * W1COLS;
        #pragma unroll
        for (int j = 0; j < 16; ++j) p[j] = fmaf(l0p, wrow[j], p[j]);
    }

    // wave shuffle-reduce, then combine 4 waves via LDS
    const int lane = t & 63;
    const int wid  = t >> 6;
    #pragma unroll
    for (int j = 0; j < 16; ++j) {
        float v = p[j];
        v += __shfl_down(v, 32);
        v += __shfl_down(v, 16);
        v += __shfl_down(v, 8);
        v += __shfl_down(v, 4);
        v += __shfl_down(v, 2);
        v += __shfl_down(v, 1);
        if (lane == 0) s_red[wid * 16 + j] = v;
    }
    __syncthreads();

    if (t < 16) {
        float x1 = s_red[t] + s_red[16 + t] + s_red[32 + t] + s_red[48 + t]
                 + b1[idx * (L2C + 1) + t];
        if (t == 15) {
            s_l1f = x1;
        } else {
            float cx = clip01(x1);
            s_v[t]       = cx * cx * cc;
            s_v[L2C + t] = cx * cc;
        }
    }
    __syncthreads();

    if (t < L3C) {
        float acc2 = b2[idx * L3C + t];
        #pragma unroll
        for (int r = 0; r < 2 * L2C; ++r)
            acc2 = fmaf(s_v[r], W2[r * W2COLS + idx * L3C + t], acc2);
        s_p2[t] = clip01(acc2) * W3[t * COUNT + idx];
    }
    __syncthreads();

    if (t == 0) {
        float s = 0.0f;
        #pragma unroll
        for (int m = 0; m < L3C; ++m) s += s_p2[m];
        out[b] = s + b3[idx] + s_l1f;
    }
}

// ---- fp32 fallback (ws too small) — R1 structure ----
__global__ __launch_bounds__(BDIM) void nnue_fused_f(
    const float* __restrict__ us,
    const float* __restrict__ them,
    const int*   __restrict__ wi,
    const float* __restrict__ wv,
    const int*   __restrict__ bi,
    const float* __restrict__ bvv,
    const int*   __restrict__ lsi,
    const float* __restrict__ W_ft,
    const float* __restrict__ b_ft,
    const float* __restrict__ W1,
    const float* __restrict__ b1,
    const float* __restrict__ W2,
    const float* __restrict__ b2,
    const float* __restrict__ W3,
    const float* __restrict__ b3,
    float* __restrict__ out)
{
    const int b = blockIdx.x;
    const int t = threadIdx.x;

    __shared__ int   s_idx[2 * K];
    __shared__ float s_val[2 * K];
    __shared__ float s_l0[2 * L1];
    __shared__ float s_red[4 * 16];
    __shared__ float s_v[2 * L2C];
    __shared__ float s_p2[L3C];
    __shared__ float s_l1f;

    if (t < K)          { s_idx[t] = wi[b * K + t];        s_val[t] = wv[b * K + t]; }
    else if (t < 2 * K) { s_idx[t] = bi[b * K + (t - K)];  s_val[t] = bvv[b * K + (t - K)]; }
    __syncthreads();

    const int c4 = t * 4;
    float4 accW = *(const float4*)(b_ft + c4);
    float4 accB = accW;

    #pragma unroll 4
    for (int k = 0; k < K; ++k) {
        const float  vwk = s_val[k];
        const float  vbk = s_val[K + k];
        const float4 rw  = *(const float4*)(W_ft + ((long)s_idx[k]     << 10) + c4);
        const float4 rb  = *(const float4*)(W_ft + ((long)s_idx[K + k] << 10) + c4);
        accW.x = fmaf(vwk, rw.x, accW.x);
        accW.y = fmaf(vwk, rw.y, accW.y);
        accW.z = fmaf(vwk, rw.z, accW.z);
        accW.w = fmaf(vwk, rw.w, accW.w);
        accB.x = fmaf(vbk, rb.x, accB.x);
        accB.y = fmaf(vbk, rb.y, accB.y);
        accB.z = fmaf(vbk, rb.z, accB.z);
        accB.w = fmaf(vbk, rb.w, accB.w);
    }

    const float u  = us[b];
    const float th = them[b];
    float4 A, Bv;
    A.x  = clip01(u * accW.x + th * accB.x);
    A.y  = clip01(u * accW.y + th * accB.y);
    A.z  = clip01(u * accW.z + th * accB.z);
    A.w  = clip01(u * accW.w + th * accB.w);
    Bv.x = clip01(u * accB.x + th * accW.x);
    Bv.y = clip01(u * accB.y + th * accW.y);
    Bv.z = clip01(u * accB.z + th * accW.z);
    Bv.w = clip01(u * accB.w + th * accW.w);
    *(float4*)(s_l0 + c4)      = A;
    *(float4*)(s_l0 + L1 + c4) = Bv;
    __syncthreads();

    const int   idx = lsi[b];
    const float cc  = 127.0f / 128.0f;

    float p[16];
    #pragma unroll
    for (int j = 0; j < 16; ++j) p[j] = 0.0f;

    const float* W1sel = W1 + idx * (L2C + 1);
    #pragma unroll
    for (int q = 0; q < 4; ++q) {
        const int e = c4 + q;
        float l0p;
        if (e < 512) l0p = s_l0[e] * s_l0[e + 512];
        else         l0p = s_l0[e + 512] * s_l0[e + 1024];
        l0p *= cc;
        const float* wrow = W1sel + e * W1COLS;
        #pragma unroll
        for (int j = 0; j < 16; ++j) p[j] = fmaf(l0p, wrow[j], p[j]);
    }

    const int lane = t & 63;
    const int wid  = t >> 6;
    #pragma unroll
    for (int j = 0; j < 16; ++j) {
        float v = p[j];
        v += __shfl_down(v, 32);
        v += __shfl_down(v, 16);
        v += __shfl_down(v, 8);
        v += __shfl_down(v, 4);
        v += __shfl_down(v, 2);
        v += __shfl_down(v, 1);
        if (lane == 0) s_red[wid * 16 + j] = v;
    }
    __syncthreads();

    if (t < 16) {
        float x1 = s_red[t] + s_red[16 + t] + s_red[32 + t] + s_red[48 + t]
                 + b1[idx * (L2C + 1) + t];
        if (t == 15) {
            s_l1f = x1;
        } else {
            float cx = clip01(x1);
            s_v[t]       = cx * cx * cc;
            s_v[L2C + t] = cx * cc;
        }
    }
    __syncthreads();

    if (t < L3C) {
        float acc = b2[idx * L3C + t];
        #pragma unroll
        for (int r = 0; r < 2 * L2C; ++r)
            acc = fmaf(s_v[r], W2[r * W2COLS + idx * L3C + t], acc);
        s_p2[t] = clip01(acc) * W3[t * COUNT + idx];
    }
    __syncthreads();

    if (t == 0) {
        float s = 0.0f;
        #pragma unroll
        for (int m = 0; m < L3C; ++m) s += s_p2[m];
        out[b] = s + b3[idx] + s_l1f;
    }
}

extern "C" void kernel_launch(void* const* d_in, const int* in_sizes, int n_in,
                              void* d_out, int out_size, void* d_ws, size_t ws_size,
                              hipStream_t stream) {
    const float* us   = (const float*)d_in[0];
    const float* them = (const float*)d_in[1];
    const int*   wi   = (const int*)  d_in[2];
    const float* wv   = (const float*)d_in[3];
    const int*   bi   = (const int*)  d_in[4];
    const float* bv   = (const float*)d_in[5];
    const int*   lsi  = (const int*)  d_in[6];
    const float* W_ft = (const float*)d_in[7];
    const float* b_ft = (const float*)d_in[8];
    const float* W1   = (const float*)d_in[9];
    const float* b1   = (const float*)d_in[10];
    const float* W2   = (const float*)d_in[11];
    const float* b2   = (const float*)d_in[12];
    const float* W3   = (const float*)d_in[13];
    const float* b3   = (const float*)d_in[14];
    float*       out  = (float*)d_out;

    const int Bn = in_sizes[0]; // 4096 batch rows
    const size_t needed = (size_t)NF * L1 * sizeof(_Float16); // 46.1 MB

    if (ws_size >= needed) {
        _Float16* Wh = (_Float16*)d_ws;
        const int n4 = (NF * L1) / 4;
        cvt_w_ft<<<2048, 256, 0, stream>>>(W_ft, Wh, n4);
        nnue_fused_h<<<Bn, BDIM, 0, stream>>>(us, them, wi, wv, bi, bv, lsi,
                                              Wh, b_ft, W1, b1, W2, b2, W3, b3, out);
    } else {
        nnue_fused_f<<<Bn, BDIM, 0, stream>>>(us, them, wi, wv, bi, bv, lsi,
                                              W_ft, b_ft, W1, b1, W2, b2, W3, b3, out);
    }
}